// Round 5
// baseline (645.323 us; speedup 1.0000x reference)
//
#include <hip/hip_runtime.h>
#include <cstdint>
#include <cstddef>

#define B_    1024
#define L_    200
#define DIN_  256
#define DOUT_ 256
#define K_    8
#define M_    (B_ * L_)   // 204800

typedef __attribute__((ext_vector_type(8))) short bf16x8;
typedef __attribute__((ext_vector_type(4))) float f32x4;

__device__ __forceinline__ float bf2f(unsigned short u) {
  union { unsigned int i; float f; } w; w.i = ((unsigned int)u) << 16; return w.f;
}
__device__ __forceinline__ unsigned short f2bf(float f) {
  union { float f; unsigned int i; } w; w.f = f;
  unsigned int x = w.i;
  return (unsigned short)((x + 0x7fffu + ((x >> 16) & 1u)) >> 16);
}

// ---------------- kernel 0: split W into bf16 hi/mid/lo in MFMA FRAGMENT ORDER.
__global__ __launch_bounds__(256)
void wt_prep(const float* __restrict__ W, unsigned short* __restrict__ Wh,
             unsigned short* __restrict__ Wm, unsigned short* __restrict__ Wl)
{
  const int k = blockIdx.x;    // 256
  const int n = threadIdx.x;   // 256
  float x = W[k * DOUT_ + n];
  unsigned short h = f2bf(x);
  float r = x - bf2f(h);
  unsigned short m = f2bf(r);
  float r2 = r - bf2f(m);
  unsigned short l = f2bf(r2);
  const int k0b = k >> 5, quad = (k >> 3) & 3, j = k & 7;
  const int nt = n >> 4, lr = n & 15;
  const size_t idx = ((((size_t)k0b * 16 + nt) * 64) + (quad * 16 + lr)) * 8 + j;
  Wh[idx] = h;
  Wm[idx] = m;
  Wl[idx] = l;
}

// ---------------- kernel 1: unchanged from R4 (208 us, MfmaUtil 32%)
__global__ __launch_bounds__(256, 2)
void gemm_mapped(const float* __restrict__ A,
                 const unsigned short* __restrict__ Wh,
                 const unsigned short* __restrict__ Wm,
                 const unsigned short* __restrict__ Wl,
                 float* __restrict__ C)
{
  const int t    = threadIdx.x;
  const int wave = t >> 6;
  const int lane = t & 63;
  const int quad = lane >> 4;
  const int lr   = lane & 15;
  const int m0   = blockIdx.x * 128 + wave * 32;

  f32x4 acc[2][16];
  #pragma unroll
  for (int mt = 0; mt < 2; ++mt)
    #pragma unroll
    for (int nt = 0; nt < 16; ++nt)
      acc[mt][nt] = (f32x4){0.f, 0.f, 0.f, 0.f};

  bf16x8 Bh[4], Bm[4], Bl[4];
  bf16x8 ah[2], am[2], al[2];
  float4 Af[2][2];

#define BLOAD(K0B, NT, S) do { \
    const size_t _off = (((size_t)(K0B) * 16 + (NT)) * 64 + lane) * 8; \
    Bh[S] = *(const bf16x8*)(Wh + _off); \
    Bm[S] = *(const bf16x8*)(Wm + _off); \
    Bl[S] = *(const bf16x8*)(Wl + _off); \
  } while (0)

  const float* ap0 = A + (size_t)(m0 + lr) * DIN_ + quad * 8;
  const float* ap1 = A + (size_t)(m0 + 16 + lr) * DIN_ + quad * 8;

  Af[0][0] = *(const float4*)(ap0);
  Af[0][1] = *(const float4*)(ap0 + 4);
  Af[1][0] = *(const float4*)(ap1);
  Af[1][1] = *(const float4*)(ap1 + 4);
  BLOAD(0, 0, 0); BLOAD(0, 1, 1); BLOAD(0, 2, 2); BLOAD(0, 3, 3);

  for (int k0b = 0; k0b < 8; ++k0b) {
    #pragma unroll
    for (int mt = 0; mt < 2; ++mt) {
      float xs[8] = {Af[mt][0].x, Af[mt][0].y, Af[mt][0].z, Af[mt][0].w,
                     Af[mt][1].x, Af[mt][1].y, Af[mt][1].z, Af[mt][1].w};
      #pragma unroll
      for (int j = 0; j < 8; ++j) {
        unsigned short h = f2bf(xs[j]);
        float r = xs[j] - bf2f(h);
        unsigned short mm = f2bf(r);
        float r2 = r - bf2f(mm);
        unsigned short ll = f2bf(r2);
        ah[mt][j] = (short)h; am[mt][j] = (short)mm; al[mt][j] = (short)ll;
      }
    }
    if (k0b < 7) {
      const int ko = (k0b + 1) * 32;
      Af[0][0] = *(const float4*)(ap0 + ko);
      Af[0][1] = *(const float4*)(ap0 + ko + 4);
      Af[1][0] = *(const float4*)(ap1 + ko);
      Af[1][1] = *(const float4*)(ap1 + ko + 4);
    }

#define GROUP(NT, S) do { \
    f32x4 c0 = acc[0][NT], c1 = acc[1][NT]; \
    c0 = __builtin_amdgcn_mfma_f32_16x16x32_bf16(ah[0], Bh[S], c0, 0, 0, 0); \
    c1 = __builtin_amdgcn_mfma_f32_16x16x32_bf16(ah[1], Bh[S], c1, 0, 0, 0); \
    c0 = __builtin_amdgcn_mfma_f32_16x16x32_bf16(ah[0], Bm[S], c0, 0, 0, 0); \
    c1 = __builtin_amdgcn_mfma_f32_16x16x32_bf16(ah[1], Bm[S], c1, 0, 0, 0); \
    c0 = __builtin_amdgcn_mfma_f32_16x16x32_bf16(am[0], Bh[S], c0, 0, 0, 0); \
    c1 = __builtin_amdgcn_mfma_f32_16x16x32_bf16(am[1], Bh[S], c1, 0, 0, 0); \
    c0 = __builtin_amdgcn_mfma_f32_16x16x32_bf16(ah[0], Bl[S], c0, 0, 0, 0); \
    c1 = __builtin_amdgcn_mfma_f32_16x16x32_bf16(ah[1], Bl[S], c1, 0, 0, 0); \
    c0 = __builtin_amdgcn_mfma_f32_16x16x32_bf16(am[0], Bm[S], c0, 0, 0, 0); \
    c1 = __builtin_amdgcn_mfma_f32_16x16x32_bf16(am[1], Bm[S], c1, 0, 0, 0); \
    c0 = __builtin_amdgcn_mfma_f32_16x16x32_bf16(al[0], Bh[S], c0, 0, 0, 0); \
    c1 = __builtin_amdgcn_mfma_f32_16x16x32_bf16(al[1], Bh[S], c1, 0, 0, 0); \
    acc[0][NT] = c0; acc[1][NT] = c1; \
  } while (0)

    GROUP(0, 0);  BLOAD(k0b, 4, 0);
    GROUP(1, 1);  BLOAD(k0b, 5, 1);
    GROUP(2, 2);  BLOAD(k0b, 6, 2);
    GROUP(3, 3);  BLOAD(k0b, 7, 3);
    GROUP(4, 0);  BLOAD(k0b, 8, 0);
    GROUP(5, 1);  BLOAD(k0b, 9, 1);
    GROUP(6, 2);  BLOAD(k0b, 10, 2);
    GROUP(7, 3);  BLOAD(k0b, 11, 3);
    GROUP(8, 0);  BLOAD(k0b, 12, 0);
    GROUP(9, 1);  BLOAD(k0b, 13, 1);
    GROUP(10, 2); BLOAD(k0b, 14, 2);
    GROUP(11, 3); BLOAD(k0b, 15, 3);
    GROUP(12, 0);
    GROUP(13, 1);
    GROUP(14, 2);
    GROUP(15, 3);
    if (k0b < 7) {
      BLOAD(k0b + 1, 0, 0); BLOAD(k0b + 1, 1, 1);
      BLOAD(k0b + 1, 2, 2); BLOAD(k0b + 1, 3, 3);
    }
#undef GROUP
  }
#undef BLOAD

  #pragma unroll
  for (int mt = 0; mt < 2; ++mt)
    #pragma unroll
    for (int nt = 0; nt < 16; ++nt)
      #pragma unroll
      for (int r = 0; r < 4; ++r) {
        int row = m0 + mt * 16 + quad * 4 + r;
        C[(size_t)row * DOUT_ + nt * 16 + lr] = acc[mt][nt][r];
      }
}

// ---------------- kernel 2 v3: one block per b; 4 waves split l (stride-16 interleave).
// Softmax: wave computes 2 capsules; Z partials LDS-combined; squash via shuffle.
__global__ __launch_bounds__(256)
void z_kernel(const float* __restrict__ mapped, const float* __restrict__ logits,
              const int* __restrict__ seq_len, float* __restrict__ caps)
{
  const int b    = blockIdx.x;
  const int t    = threadIdx.x;
  const int lane = t & 63;
  const int wave = t >> 6;
  const int len  = seq_len[b];          // 1..200
  __shared__ float w[K_][204];          // 6.5 KB
  __shared__ float red[4][K_][DOUT_];   // 32 KB

  #pragma unroll
  for (int kk = 0; kk < 2; ++kk) {
    const int k = wave * 2 + kk;
    float v[4];
    float mx = -3.4028235e38f;
    #pragma unroll
    for (int i = 0; i < 4; ++i) {
      int l = lane + 64 * i;
      v[i] = (l < len) ? logits[k * L_ + l] : -3.4028235e38f;
      mx = fmaxf(mx, v[i]);
    }
    #pragma unroll
    for (int s = 1; s < 64; s <<= 1) mx = fmaxf(mx, __shfl_xor(mx, s, 64));
    float e[4]; float sum = 0.f;
    #pragma unroll
    for (int i = 0; i < 4; ++i) {
      int l = lane + 64 * i;
      e[i] = (l < len) ? __expf(v[i] - mx) : 0.f;
      sum += e[i];
    }
    #pragma unroll
    for (int s = 1; s < 64; s <<= 1) sum += __shfl_xor(sum, s, 64);
    float inv = 1.f / sum;
    #pragma unroll
    for (int i = 0; i < 4; ++i) {
      int l = lane + 64 * i;
      if (l < 204) w[k][l] = e[i] * inv;   // exactly 0 for l >= len
    }
  }
  __syncthreads();

  // Z: lane owns 4 channels; wave handles l = wave*4 + 16*i
  f32x4 acc[K_];
  #pragma unroll
  for (int k = 0; k < K_; ++k) acc[k] = (f32x4){0.f, 0.f, 0.f, 0.f};
  const float* mp = mapped + (size_t)b * L_ * DOUT_ + lane * 4;
  const int lceil = (len + 3) & ~3;
  for (int l = wave * 4; l < lceil; l += 16) {
    float4 m0 = *(const float4*)(mp + (size_t)(l + 0) * DOUT_);
    float4 m1 = *(const float4*)(mp + (size_t)(l + 1) * DOUT_);
    float4 m2 = *(const float4*)(mp + (size_t)(l + 2) * DOUT_);
    float4 m3 = *(const float4*)(mp + (size_t)(l + 3) * DOUT_);
    #pragma unroll
    for (int k = 0; k < K_; ++k) {
      float4 wv = *(const float4*)&w[k][l];
      f32x4 c = acc[k];
      c.x += wv.x * m0.x + wv.y * m1.x + wv.z * m2.x + wv.w * m3.x;
      c.y += wv.x * m0.y + wv.y * m1.y + wv.z * m2.y + wv.w * m3.y;
      c.z += wv.x * m0.z + wv.y * m1.z + wv.z * m2.z + wv.w * m3.z;
      c.w += wv.x * m0.w + wv.y * m1.w + wv.z * m2.w + wv.w * m3.w;
      acc[k] = c;
    }
  }
  #pragma unroll
  for (int k = 0; k < K_; ++k)
    *(f32x4*)&red[wave][k][lane * 4] = acc[k];
  __syncthreads();

  // combine + squash: wave handles capsules 2w, 2w+1
  #pragma unroll
  for (int kk = 0; kk < 2; ++kk) {
    const int k = wave * 2 + kk;
    float4 s0 = *(const float4*)&red[0][k][lane * 4];
    float4 s1 = *(const float4*)&red[1][k][lane * 4];
    float4 s2 = *(const float4*)&red[2][k][lane * 4];
    float4 s3 = *(const float4*)&red[3][k][lane * 4];
    float4 z;
    z.x = (s0.x + s1.x) + (s2.x + s3.x);
    z.y = (s0.y + s1.y) + (s2.y + s3.y);
    z.z = (s0.z + s1.z) + (s2.z + s3.z);
    z.w = (s0.w + s1.w) + (s2.w + s3.w);
    float sq = z.x * z.x + z.y * z.y + z.z * z.z + z.w * z.w;
    #pragma unroll
    for (int s = 1; s < 64; s <<= 1) sq += __shfl_xor(sq, s, 64);
    float scale = sq / ((1.f + sq) * sqrtf(sq + 1e-8f));
    float4 o;
    o.x = scale * z.x; o.y = scale * z.y; o.z = scale * z.z; o.w = scale * z.w;
    *(float4*)&caps[((size_t)b * K_ + k) * DOUT_ + lane * 4] = o;
  }
}

// ---------------- kernel 3 v3: block = (lc: 16 l, bc: 16 b); waves in 2x2 (b-half, l-half).
// acc 8x8 per wave; shuffle-reduce; LDS cross-wave combine; deterministic partials[64][K][L].
__global__ __launch_bounds__(256)
void delta_kernel(const float* __restrict__ mapped, const float* __restrict__ caps,
                  float* __restrict__ partials)
{
  const int t    = threadIdx.x;
  const int lane = t & 63;
  const int wave = t >> 6;
  const int lc   = blockIdx.x % 13;   // 13 chunks of 16 l (208 >= 200, tail masked)
  const int bc   = blockIdx.x / 13;   // 64 chunks of 16 b
  const int bsub = (wave >> 1) * 8;   // waves 0,1 -> b 0..7 ; waves 2,3 -> b 8..15
  const int lsub = (wave & 1) * 8;    // waves 0,2 -> l 0..7 ; waves 1,3 -> l 8..15
  const int l0   = lc * 16 + lsub;
  const int b0   = bc * 16 + bsub;
  const int o4   = lane * 4;

  float acc[K_][8];
  #pragma unroll
  for (int k = 0; k < K_; ++k)
    #pragma unroll
    for (int ll = 0; ll < 8; ++ll) acc[k][ll] = 0.f;

  for (int bi = 0; bi < 8; ++bi) {
    const int b = b0 + bi;
    const float* cp = caps + (size_t)b * (K_ * DOUT_) + o4;
    const float* mp = mapped + ((size_t)b * L_ + l0) * DOUT_ + o4;
    float4 cv[K_], mv[8];
    #pragma unroll
    for (int k = 0; k < K_; ++k) cv[k] = *(const float4*)(cp + (size_t)k * DOUT_);
    #pragma unroll
    for (int ll = 0; ll < 8; ++ll) {
      mv[ll] = (l0 + ll < L_) ? *(const float4*)(mp + (size_t)ll * DOUT_)
                              : make_float4(0.f, 0.f, 0.f, 0.f);
    }
    #pragma unroll
    for (int k = 0; k < K_; ++k)
      #pragma unroll
      for (int ll = 0; ll < 8; ++ll)
        acc[k][ll] += cv[k].x * mv[ll].x + cv[k].y * mv[ll].y
                    + cv[k].z * mv[ll].z + cv[k].w * mv[ll].w;
  }

  // 64 (k,ll) values per wave: shuffle-reduce over 64 lanes; lane k*8+ll keeps its value
  float out = 0.f;
  #pragma unroll
  for (int k = 0; k < K_; ++k)
    #pragma unroll
    for (int ll = 0; ll < 8; ++ll) {
      float v = acc[k][ll];
      v += __shfl_xor(v, 1, 64);
      v += __shfl_xor(v, 2, 64);
      v += __shfl_xor(v, 4, 64);
      v += __shfl_xor(v, 8, 64);
      v += __shfl_xor(v, 16, 64);
      v += __shfl_xor(v, 32, 64);
      if (lane == k * 8 + ll) out = v;
    }
  __shared__ float red[4][64];
  red[wave][lane] = out;
  __syncthreads();
  if (wave < 2) {
    // wave 0: l-half 0 = waves {0,2}; wave 1: l-half 1 = waves {1,3}
    float v = red[wave][lane] + red[wave + 2][lane];
    const int k  = lane >> 3;
    const int ll = lane & 7;
    const int gl = lc * 16 + wave * 8 + ll;
    if (gl < L_) partials[((size_t)bc * K_ + k) * L_ + gl] = v;
  }
}

// ---------------- small kernels
__global__ __launch_bounds__(256)
void init_logits(const float* __restrict__ rlog, float* __restrict__ logits)
{
  int i = blockIdx.x * 256 + threadIdx.x;
  if (i < K_ * L_) logits[i] = rlog[i];
}

__global__ __launch_bounds__(256)
void reduce_kernel(const float* __restrict__ partials, float* __restrict__ logits)
{
  int i = blockIdx.x * 256 + threadIdx.x;
  if (i < K_ * L_) {
    float s = 0.f;
    #pragma unroll 4
    for (int bc = 0; bc < 64; ++bc) s += partials[bc * (K_ * L_) + i];
    logits[i] += s;
  }
}

extern "C" void kernel_launch(void* const* d_in, const int* in_sizes, int n_in,
                              void* d_out, int out_size, void* d_ws, size_t ws_size,
                              hipStream_t stream)
{
  const float* behav = (const float*)d_in[0];
  const int*   slen  = (const int*)d_in[1];
  const float* rlog  = (const float*)d_in[2];
  const float* W     = (const float*)d_in[3];
  float* caps = (float*)d_out;

  char* ws = (char*)d_ws;
  float* logitsW  = (float*)ws;                           // 6400 B
  float* partials = (float*)(ws + 8192);                  // 409600 B (ends 417792)
  unsigned short* Wh = (unsigned short*)(ws + 458752);    // 128 KiB each
  unsigned short* Wm = (unsigned short*)(ws + 589824);
  unsigned short* Wl = (unsigned short*)(ws + 720896);    // ends 851968 < 1 MiB
  float* mapped   = (float*)(ws + (1 << 20));             // 200 MiB fp32

  init_logits<<<dim3(7), 256, 0, stream>>>(rlog, logitsW);
  wt_prep<<<dim3(256), 256, 0, stream>>>(W, Wh, Wm, Wl);
  gemm_mapped<<<dim3(1600), 256, 0, stream>>>(behav, Wh, Wm, Wl, mapped);
  for (int it = 0; it < 3; ++it) {
    z_kernel<<<dim3(B_), 256, 0, stream>>>(mapped, logitsW, slen, caps);
    if (it < 2) {   // delta after the last iteration is dead code in the reference
      delta_kernel<<<dim3(13 * 64), 256, 0, stream>>>(mapped, caps, partials);
      reduce_kernel<<<dim3(7), 256, 0, stream>>>(partials, logitsW);
    }
  }
}